// Round 1
// baseline (423.082 us; speedup 1.0000x reference)
//
#include <hip/hip_runtime.h>
#include <hip/hip_bf16.h>

#define NN 51200
#define EE 819200
#define BB 64

typedef __attribute__((ext_vector_type(8))) short short8;
typedef __attribute__((ext_vector_type(4))) float f32x4;

__device__ __forceinline__ ushort f2bf(float f) {
    unsigned int u = __float_as_uint(f);
    unsigned int r = (u + 0x7FFFu + ((u >> 16) & 1u)) >> 16;   // RNE, finite inputs
    return (ushort)r;
}

// ---------------- weight prep: fragment-ordered bf16 ----------------
// Layout: Wp[((ks*4+g)*N + n)*8 + i] = W[(ks*32 + g*8 + i)*N + n]
// so lane l (lr=l&15, lg=l>>4) reads its B-frag for (ks, tile n0) as 16B at
// ((ks*4+lg)*N + n0+lr)*8 elements.
__global__ void prep_weights(const float* __restrict__ gW1, const float* __restrict__ gW2,
                             const float* __restrict__ lW1,
                             ushort* __restrict__ W1p, ushort* __restrict__ W2p,
                             ushort* __restrict__ L1p) {
    int tid = threadIdx.x;
    for (int idx = tid; idx < 128 * 128; idx += 256) {          // gW1 [128][128]
        int i = idx & 7, n = (idx >> 3) & 127, q = idx >> 10;   // q = ks*4+g
        int k = (q >> 2) * 32 + (q & 3) * 8 + i;
        W1p[idx] = f2bf(gW1[k * 128 + n]);
    }
    for (int idx = tid; idx < 128 * 64; idx += 256) {           // gW2 [128][64]
        int i = idx & 7, n = (idx >> 3) & 63, q = idx >> 9;
        int k = (q >> 2) * 32 + (q & 3) * 8 + i;
        W2p[idx] = f2bf(gW2[k * 64 + n]);
    }
    for (int idx = tid; idx < 256 * 128; idx += 256) {          // lW1 [256][128]
        int i = idx & 7, n = (idx >> 3) & 127, q = idx >> 10;   // ks = q>>2 in 0..7
        int k = (q >> 2) * 32 + (q & 3) * 8 + i;
        L1p[idx] = f2bf(lW1[k * 128 + n]);
    }
}

// ---------------- global conv: h=[x[dst],x[src]] -> relu(h@W1+b1)@W2+b2 -> atomic g[dst] ----------------
__global__ __launch_bounds__(512, 2) void global_conv(
        const float* __restrict__ x, const int* __restrict__ eidx,
        const ushort* __restrict__ W1p, const ushort* __restrict__ W2p,
        const float* __restrict__ gb1, const float* __restrict__ gb2,
        float* __restrict__ g) {
    // 80 KB LDS -> 2 blocks/CU. sH doubles as Hid (each wave overwrites its own rows).
    __shared__ __attribute__((aligned(16))) ushort sH[128 * 128];
    __shared__ __attribute__((aligned(16))) ushort sW1[128 * 128];
    __shared__ __attribute__((aligned(16))) ushort sW2[128 * 64];

    const int tid = threadIdx.x;
    const int ebase = blockIdx.x * 128;

    // stage fragment-ordered weights (linear, conflict-free)
    {
        const uint4* s1 = reinterpret_cast<const uint4*>(W1p);
        uint4* d1 = reinterpret_cast<uint4*>(sW1);
        for (int c = tid; c < 2048; c += 512) d1[c] = s1[c];
        const uint4* s2 = reinterpret_cast<const uint4*>(W2p);
        uint4* d2 = reinterpret_cast<uint4*>(sW2);
        for (int c = tid; c < 1024; c += 512) d2[c] = s2[c];
    }
    // gather H[er][0:64]=x[dst], H[er][64:128]=x[src], bf16, XOR-swizzled rows
    {
        const int er = tid >> 2, q = tid & 3;
        const int e = ebase + er;
        const int node = (q < 2) ? eidx[EE + e] : eidx[e];      // row1=dst, row0=src
        const float4* srcp = reinterpret_cast<const float4*>(x + (long)node * 64 + (q & 1) * 32);
        const int swz = (er & 7) << 3;                          // element-index XOR
        ushort* rowp = sH + er * 128;
#pragma unroll
        for (int jj = 0; jj < 4; ++jj) {
            float4 f0 = srcp[jj * 2], f1 = srcp[jj * 2 + 1];
            short8 v;
            v[0] = (short)f2bf(f0.x); v[1] = (short)f2bf(f0.y);
            v[2] = (short)f2bf(f0.z); v[3] = (short)f2bf(f0.w);
            v[4] = (short)f2bf(f1.x); v[5] = (short)f2bf(f1.y);
            v[6] = (short)f2bf(f1.z); v[7] = (short)f2bf(f1.w);
            int col = q * 32 + jj * 8;
            *reinterpret_cast<short8*>(rowp + (col ^ swz)) = v;
        }
    }
    __syncthreads();

    const int w = tid >> 6, l = tid & 63, lr = l & 15, lg = l >> 4;
    const int arow = w * 16 + lr;
    const int aswz = (arow & 7) << 3;

    // GEMM1: Hid[128][128] = relu(H @ W1 + b1)
    f32x4 acc[8] = {};
#pragma unroll
    for (int ks = 0; ks < 4; ++ks) {
        short8 a = *reinterpret_cast<const short8*>(sH + arow * 128 + ((ks * 32 + lg * 8) ^ aswz));
#pragma unroll
        for (int t = 0; t < 8; ++t) {
            short8 b = *reinterpret_cast<const short8*>(sW1 + ((ks * 4 + lg) * 128 + t * 16 + lr) * 8);
            acc[t] = __builtin_amdgcn_mfma_f32_16x16x32_bf16(a, b, acc[t], 0, 0, 0);
        }
    }
    // bias+relu, write Hid back into sH rows (own wave's rows only)
#pragma unroll
    for (int t = 0; t < 8; ++t) {
        float b1 = gb1[t * 16 + lr];
#pragma unroll
        for (int i = 0; i < 4; ++i) {
            int hrow = w * 16 + lg * 4 + i;
            int hcol = t * 16 + lr;
            sH[hrow * 128 + (hcol ^ ((hrow & 7) << 3))] = f2bf(fmaxf(acc[t][i] + b1, 0.0f));
        }
    }
    __syncthreads();

    // GEMM2: M[128][64] = Hid @ W2
    f32x4 acc2[4] = {};
#pragma unroll
    for (int ks = 0; ks < 4; ++ks) {
        short8 a = *reinterpret_cast<const short8*>(sH + arow * 128 + ((ks * 32 + lg * 8) ^ aswz));
#pragma unroll
        for (int t = 0; t < 4; ++t) {
            short8 b = *reinterpret_cast<const short8*>(sW2 + ((ks * 4 + lg) * 64 + t * 16 + lr) * 8);
            acc2[t] = __builtin_amdgcn_mfma_f32_16x16x32_bf16(a, b, acc2[t], 0, 0, 0);
        }
    }
    // scatter: g[dst] += M  (fp32 atomics)
    int dstn[4];
#pragma unroll
    for (int i = 0; i < 4; ++i) dstn[i] = eidx[EE + ebase + w * 16 + lg * 4 + i];
#pragma unroll
    for (int t = 0; t < 4; ++t) {
        float b2 = gb2[t * 16 + lr];
#pragma unroll
        for (int i = 0; i < 4; ++i)
            atomicAdd(&g[(long)dstn[i] * 64 + t * 16 + lr], acc2[t][i] + b2);
    }
}

// ---------------- pooling: pooled[b] = sum_{batch[n]==b} e[n]*g[n]  (batch sorted) ----------------
__global__ void pool_kernel(const float* __restrict__ g, const float* __restrict__ e,
                            const int* __restrict__ batch, float* __restrict__ pooled) {
    __shared__ float red[4][64];
    int tid = threadIdx.x;
    int nb = blockIdx.x * 64;
    int c = tid & 63, grp = tid >> 6;
    int b0 = batch[nb], b1 = batch[nb + 63];
    if (b0 == b1) {                       // whole block in one segment (common: batch sorted)
        float s = 0.f;
        for (int j = 0; j < 16; ++j) {
            int node = nb + grp * 16 + j;
            s += e[node] * g[(long)node * 64 + c];
        }
        red[grp][c] = s;
        __syncthreads();
        if (grp == 0)
            atomicAdd(&pooled[b0 * 64 + c], red[0][c] + red[1][c] + red[2][c] + red[3][c]);
    } else {                              // boundary block: per-node atomics
        for (int j = 0; j < 16; ++j) {
            int node = nb + grp * 16 + j;
            atomicAdd(&pooled[batch[node] * 64 + c], e[node] * g[(long)node * 64 + c]);
        }
    }
}

// ---------------- xl[n] = bf16(concat(x[n], pooled[batch[n]])) ----------------
__global__ void build_xl(const float* __restrict__ x, const float* __restrict__ pooled,
                         const int* __restrict__ batch, ushort* __restrict__ xl) {
    int idx = blockIdx.x * 256 + threadIdx.x;     // < N*16
    int node = idx >> 4, ch = idx & 15;
    const float4* base;
    if (ch < 8) base = reinterpret_cast<const float4*>(x + (long)node * 64 + ch * 8);
    else        base = reinterpret_cast<const float4*>(pooled + (long)batch[node] * 64 + (ch - 8) * 8);
    float4 f0 = base[0], f1 = base[1];
    short8 v;
    v[0] = (short)f2bf(f0.x); v[1] = (short)f2bf(f0.y);
    v[2] = (short)f2bf(f0.z); v[3] = (short)f2bf(f0.w);
    v[4] = (short)f2bf(f1.x); v[5] = (short)f2bf(f1.y);
    v[6] = (short)f2bf(f1.z); v[7] = (short)f2bf(f1.w);
    *reinterpret_cast<short8*>(xl + (long)node * 128 + ch * 8) = v;
}

// ---------------- local conv: h=[xl[dst],xl[src]](256) -> relu(h@lW1+lb1)@lW2+lb2 -> atomic w[dst] ----------------
__global__ __launch_bounds__(512, 1) void local_conv(
        const ushort* __restrict__ xl, const int* __restrict__ eidx,
        const ushort* __restrict__ L1p, const float* __restrict__ lb1,
        const float* __restrict__ lW2, const float* __restrict__ lb2,
        float* __restrict__ out) {
    __shared__ __attribute__((aligned(16))) ushort sH[128 * 256];   // 64 KB
    __shared__ __attribute__((aligned(16))) ushort sW[256 * 128];   // 64 KB

    const int tid = threadIdx.x;
    const int ebase = blockIdx.x * 128;

    {
        const uint4* s1 = reinterpret_cast<const uint4*>(L1p);
        uint4* d1 = reinterpret_cast<uint4*>(sW);
        for (int c = tid; c < 4096; c += 512) d1[c] = s1[c];
    }
    {
        const int er = tid >> 2, q = tid & 3;
        const int e = ebase + er;
        const int node = (q < 2) ? eidx[EE + e] : eidx[e];
        const uint4* srcp = reinterpret_cast<const uint4*>(xl + (long)node * 128 + (q & 1) * 64);
        const int swz = (er & 7) << 3;
        ushort* rowp = sH + er * 256;
#pragma unroll
        for (int jj = 0; jj < 8; ++jj) {
            uint4 v = srcp[jj];
            int col = q * 64 + jj * 8;
            *reinterpret_cast<uint4*>(rowp + (col ^ swz)) = v;
        }
    }
    __syncthreads();

    const int w = tid >> 6, l = tid & 63, lr = l & 15, lg = l >> 4;
    const int arow = w * 16 + lr;
    const int aswz = (arow & 7) << 3;

    f32x4 acc[8] = {};
#pragma unroll
    for (int ks = 0; ks < 8; ++ks) {
        short8 a = *reinterpret_cast<const short8*>(sH + arow * 256 + ((ks * 32 + lg * 8) ^ aswz));
#pragma unroll
        for (int t = 0; t < 8; ++t) {
            short8 b = *reinterpret_cast<const short8*>(sW + ((ks * 4 + lg) * 128 + t * 16 + lr) * 8);
            acc[t] = __builtin_amdgcn_mfma_f32_16x16x32_bf16(a, b, acc[t], 0, 0, 0);
        }
    }
    // relu + matvec with lW2, fully in registers
    float part[4] = {0.f, 0.f, 0.f, 0.f};
#pragma unroll
    for (int t = 0; t < 8; ++t) {
        float b1 = lb1[t * 16 + lr];
        float w2 = lW2[t * 16 + lr];
#pragma unroll
        for (int i = 0; i < 4; ++i)
            part[i] += fmaxf(acc[t][i] + b1, 0.0f) * w2;
    }
#pragma unroll
    for (int m = 1; m < 16; m <<= 1) {
#pragma unroll
        for (int i = 0; i < 4; ++i)
            part[i] += __shfl_xor(part[i], m, 64);
    }
    if (lr < 4) {
        int row = w * 16 + lg * 4 + lr;
        int dstn = eidx[EE + ebase + row];
        atomicAdd(&out[dstn], part[lr] + lb2[0]);
    }
}

extern "C" void kernel_launch(void* const* d_in, const int* in_sizes, int n_in,
                              void* d_out, int out_size, void* d_ws, size_t ws_size,
                              hipStream_t stream) {
    const float* x   = (const float*)d_in[0];
    const float* e   = (const float*)d_in[1];
    const int*   ei  = (const int*)d_in[2];
    const int*   bat = (const int*)d_in[3];
    const float* gW1 = (const float*)d_in[4];
    const float* gb1 = (const float*)d_in[5];
    const float* gW2 = (const float*)d_in[6];
    const float* gb2 = (const float*)d_in[7];
    const float* lW1 = (const float*)d_in[8];
    const float* lb1 = (const float*)d_in[9];
    const float* lW2 = (const float*)d_in[10];
    const float* lb2 = (const float*)d_in[11];

    char* ws = (char*)d_ws;
    ushort* W1p    = (ushort*)(ws);                       // 32768 B
    ushort* W2p    = (ushort*)(ws + 32768);               // 16384 B
    ushort* L1p    = (ushort*)(ws + 49152);               // 65536 B
    float*  g      = (float*)(ws + 114688);               // N*64*4 = 13107200 B
    float*  pooled = (float*)(ws + 114688 + 13107200);    // 64*64*4 = 16384 B
    ushort* xl     = (ushort*)(ws + 114688 + 13107200 + 16384);  // N*128*2 = 13107200 B

    hipMemsetAsync(g, 0, 13107200 + 16384, stream);                 // g + pooled
    hipMemsetAsync(d_out, 0, (size_t)out_size * sizeof(float), stream);

    prep_weights<<<1, 256, 0, stream>>>(gW1, gW2, lW1, W1p, W2p, L1p);
    global_conv<<<EE / 128, 512, 0, stream>>>(x, ei, W1p, W2p, gb1, gb2, g);
    pool_kernel<<<NN / 64, 256, 0, stream>>>(g, e, bat, pooled);
    build_xl<<<NN * 16 / 256, 256, 0, stream>>>(x, pooled, bat, xl);
    local_conv<<<EE / 128, 512, 0, stream>>>(xl, ei, L1p, lb1, lW2, lb2, (float*)d_out);
}